// Round 7
// baseline (234.425 us; speedup 1.0000x reference)
//
#include <hip/hip_runtime.h>
#include <hip/hip_bf16.h>
#include <stdint.h>

#define N_ROWS 16384

typedef __bf16 bf16x8 __attribute__((ext_vector_type(8)));
typedef float f32x4 __attribute__((ext_vector_type(4)));

#define AS1 __attribute__((address_space(1)))
#define AS3 __attribute__((address_space(3)))

// ---------------- ws layout (bytes) ----------------
// WcS : (W_token@W_qkv)^T bf16 [384][768], 8-elt chunks XOR-swizzled   589824
// bc  : f32 [384]  (b_token@W_qkv + b_qkv)                               1536
// qb  : bf16 [16384][128]  (q * -log2e)                               4194304
// kb  : bf16 [16384][128]  (XOR-swizzled, staged via global_load_lds) 4194304
// wv  : f32  [16384]  ((v+bias) . W_fc)                                 65536
// part: f32  [8][16384]                                                524288
#define OFF_WCS  0u
#define OFF_BC   589824u
#define OFF_QB   591360u
#define OFF_KB   4785664u
#define OFF_WV   8979968u
#define OFF_PART 9045504u

// ---- kernel 0: Wc = W_token @ W_qkv -> bf16, [n][768] with 8-elt chunk XOR swizzle;
//      bc = b_token @ W_qkv + b_qkv ----
__global__ void prep(const float* __restrict__ Wt, const float* __restrict__ Wq,
                     const float* __restrict__ bt, const float* __restrict__ bq,
                     __bf16* __restrict__ WcS, float* __restrict__ bc) {
    int u = blockIdx.x * 256 + threadIdx.x;          // [0, 768*96)
    if (u < 768 * 96) {
        int k = u / 96, n4 = u % 96;
        float s[4] = {0, 0, 0, 0};
        const float* wtp = Wt + k * 128;
        const float* wqp = Wq + n4 * 4;
#pragma unroll 8
        for (int d = 0; d < 128; d++) {
            float a = wtp[d];
            float4 b = *(const float4*)(wqp + d * 384);
            s[0] += a * b.x; s[1] += a * b.y; s[2] += a * b.z; s[3] += a * b.w;
        }
        int kb_ = k >> 6, c = (k >> 3) & 7, k7 = k & 7;
#pragma unroll
        for (int j = 0; j < 4; j++) {
            int n = n4 * 4 + j;
            WcS[n * 768 + kb_ * 64 + ((c ^ (n & 7)) << 3) + k7] = (__bf16)s[j];
        }
    }
    if (u < 384) {
        float s = bq[u];
        for (int d = 0; d < 128; d++) s += bt[d] * Wq[d * 384 + u];
        bc[u] = s;
    }
}

// ---- kernel 1: qkv = bf16(x) @ Wc + bc via LDS-staged tiled GEMM ----
// (R5 version, reverted: the BN=384 fusion regressed ~14 us.)
// BM=64, BN=128, BK=64; grid (256, 3); sp aligns with q / k / v+wv epilogues.
__launch_bounds__(256)
__global__ void gemm_qkv(const float* __restrict__ x, const __bf16* __restrict__ WcS,
                         const float* __restrict__ bc, const float* __restrict__ W_fc,
                         __bf16* __restrict__ qb, __bf16* __restrict__ kb,
                         float* __restrict__ wv) {
    __shared__ float  Asm[64 * 64];    // fp32 A tile, 32B-pair XOR-swizzled
    __shared__ __bf16 Bsm[128 * 64];   // bf16 B tile, 16B-chunk XOR-swizzled
    __shared__ float  wred[64];
    const int tid = threadIdx.x, wave = tid >> 6, lane = tid & 63;
    const int n16 = lane & 15, q = lane >> 4;
    const int mh = wave >> 1, nw = wave & 1;
    const int row0 = blockIdx.x * 64;
    const int sp = blockIdx.y;

    // per-lane staging source pointers (swizzle baked into the global address)
    const char* aptr[4];
    const char* bptr[4];
    {
        int p = (lane & 15) >> 1, half = lane & 1;
#pragma unroll
        for (int i = 0; i < 4; i++) {
            int ar = row0 + wave * 16 + i * 4 + (lane >> 4);
            aptr[i] = (const char*)x + (size_t)ar * 3072 + ((p ^ (ar & 7)) * 8 + half * 4) * 4;
            int br = sp * 128 + wave * 32 + i * 8 + (lane >> 3);
            bptr[i] = (const char*)WcS + (size_t)br * 1536 + (lane & 7) * 16;
        }
    }
    f32x4 acc[2][4];
#pragma unroll
    for (int mt = 0; mt < 2; mt++)
#pragma unroll
        for (int t = 0; t < 4; t++) acc[mt][t] = (f32x4){0, 0, 0, 0};

    for (int kbi = 0; kbi < 12; kbi++) {
#pragma unroll
        for (int i = 0; i < 4; i++)
            __builtin_amdgcn_global_load_lds((const AS1 void*)(aptr[i] + kbi * 256),
                (AS3 void*)((char*)Asm + wave * 4096 + i * 1024), 16, 0, 0);
#pragma unroll
        for (int i = 0; i < 4; i++)
            __builtin_amdgcn_global_load_lds((const AS1 void*)(bptr[i] + kbi * 128),
                (AS3 void*)((char*)Bsm + wave * 4096 + i * 1024), 16, 0, 0);
        __syncthreads();
#pragma unroll
        for (int ks = 0; ks < 2; ks++) {
            const int swz = ((ks * 4 + q) ^ (n16 & 7)) << 3;
            bf16x8 af[2];
#pragma unroll
            for (int mt = 0; mt < 2; mt++) {
                const float* ap = Asm + (mh * 32 + mt * 16 + n16) * 64 + swz;
                f32x4 a0 = *(const f32x4*)ap;
                f32x4 a1 = *(const f32x4*)(ap + 4);
                bf16x8 t;
                t[0] = (__bf16)a0[0]; t[1] = (__bf16)a0[1]; t[2] = (__bf16)a0[2]; t[3] = (__bf16)a0[3];
                t[4] = (__bf16)a1[0]; t[5] = (__bf16)a1[1]; t[6] = (__bf16)a1[2]; t[7] = (__bf16)a1[3];
                af[mt] = t;
            }
#pragma unroll
            for (int t = 0; t < 4; t++) {
                bf16x8 bf = *(const bf16x8*)(Bsm + (nw * 64 + t * 16 + n16) * 64 + swz);
                acc[0][t] = __builtin_amdgcn_mfma_f32_16x16x32_bf16(af[0], bf, acc[0][t], 0, 0, 0);
                acc[1][t] = __builtin_amdgcn_mfma_f32_16x16x32_bf16(af[1], bf, acc[1][t], 0, 0, 0);
            }
        }
        __syncthreads();
    }

    // epilogue: cols of this block = sp*128 + nw*64 + t*16 + n16
    const int clb = nw * 64 + n16;
    if (sp == 0) {
#pragma unroll
        for (int t = 0; t < 4; t++) {
            int cl = clb + t * 16;
            float bcv = bc[cl];
#pragma unroll
            for (int mt = 0; mt < 2; mt++)
#pragma unroll
                for (int r = 0; r < 4; r++) {
                    int row = row0 + mh * 32 + mt * 16 + q * 4 + r;
                    qb[row * 128 + cl] = (__bf16)((acc[mt][t][r] + bcv) * -1.44269504088896f);
                }
        }
    } else if (sp == 1) {
        // kb XOR-swizzled (16-chunk index ^ row&15) so attn's linear
        // global_load_lds + swizzled ds_read is bank-conflict-free.
#pragma unroll
        for (int t = 0; t < 4; t++) {
            int d = clb + t * 16;
            float bcv = bc[128 + d];
#pragma unroll
            for (int mt = 0; mt < 2; mt++)
#pragma unroll
                for (int r = 0; r < 4; r++) {
                    int row = row0 + mh * 32 + mt * 16 + q * 4 + r;
                    kb[row * 128 + (((d >> 3) ^ (row & 15)) << 3) + (d & 7)] = (__bf16)(acc[mt][t][r] + bcv);
                }
        }
    } else {
        float wacc[2][4] = {{0, 0, 0, 0}, {0, 0, 0, 0}};
#pragma unroll
        for (int t = 0; t < 4; t++) {
            int cl = clb + t * 16;
            float bcv = bc[256 + cl];
            float wf = W_fc[cl];
#pragma unroll
            for (int mt = 0; mt < 2; mt++)
#pragma unroll
                for (int r = 0; r < 4; r++) wacc[mt][r] += (acc[mt][t][r] + bcv) * wf;
        }
        float vred[2][4];
#pragma unroll
        for (int mt = 0; mt < 2; mt++)
#pragma unroll
            for (int r = 0; r < 4; r++) {
                float v = wacc[mt][r];
                v += __shfl_xor(v, 1, 64);
                v += __shfl_xor(v, 2, 64);
                v += __shfl_xor(v, 4, 64);
                v += __shfl_xor(v, 8, 64);
                vred[mt][r] = v;
                if (nw == 0 && n16 == 0) wred[mh * 32 + mt * 16 + q * 4 + r] = v;
            }
        __syncthreads();
        if (nw == 1 && n16 == 0) {
#pragma unroll
            for (int mt = 0; mt < 2; mt++)
#pragma unroll
                for (int r = 0; r < 4; r++) {
                    int lr = mh * 32 + mt * 16 + q * 4 + r;
                    wv[row0 + lr] = wred[lr] + vred[mt][r];
                }
        }
    }
}

// ---- kernel 2: partial[sp][i] = sum_{j in slice sp} sigmoid(q_i.k_j) * wv_j ----
// v7: pair-barrier pipeline. LDS = kbuf ONLY (32 KB exactly -> 4 blocks/CU
// guaranteed; R5/R6's 40 KB fit only 3, matching the 30% occupancy). Per pair
// of 32-row chunks: vmcnt(0) -> s_barrier -> ISSUE(next pair) -> compute
// (4 t-steps, deferred sigmoid). 32 barriers (was 64). At the vmcnt(0) the
// only outstanding vmem is the previous pair's staging, issued one full pair
// of compute earlier -> no stall. ISSUE-after-barrier overwrite safety:
// pair p's ISSUE targets pair p-1's slots; barrier(p) guarantees all waves
// finished computing pair p-1. wv weights: 4 per-lane dword loads per pair
// (XCD-local L2-hot; vmcnt(0) scheme tolerates them).
__launch_bounds__(256, 4)
__global__ void attn(const __bf16* __restrict__ qb, const __bf16* __restrict__ kb,
                     const float* __restrict__ wv, float* __restrict__ partial) {
    __shared__ __bf16 kbuf[4 * 32 * 128];   // 32 KB ring, sole LDS use
    const int tid = threadIdx.x;
    const int wave = tid >> 6, lane = tid & 63;
    const int n16 = lane & 15, q = lane >> 4;
    const int bid = blockIdx.x;
    const int sp = bid & 7;                  // XCD-pinned k-slice
    const int rb = bid >> 3;                 // [0,128) row block
    const int row0 = rb * 128 + wave * 32;
    const int jb0 = sp * 2048;

    // q fragments: 32 rows x 128 d, resident in 32 VGPRs
    bf16x8 qf[2][4];
#pragma unroll
    for (int mt = 0; mt < 2; mt++)
#pragma unroll
        for (int ks = 0; ks < 4; ks++)
            qf[mt][ks] = *(const bf16x8*)(qb + (size_t)(row0 + mt * 16 + n16) * 128 + ks * 32 + q * 8);
    __builtin_amdgcn_sched_barrier(0);

    // each wave stages 2 KB (2 x 1 KB) of each 8 KB chunk
    auto ISSUE = [&](int c, int slot) {
        const char* gsrc = (const char*)kb + (size_t)(jb0 + c * 32) * 256 + wave * 2048;
        char* gdst = (char*)kbuf + slot * 8192 + wave * 2048;
        __builtin_amdgcn_global_load_lds((const AS1 void*)(gsrc + lane * 16),
                                         (AS3 void*)gdst, 16, 0, 0);
        __builtin_amdgcn_global_load_lds((const AS1 void*)(gsrc + 1024 + lane * 16),
                                         (AS3 void*)(gdst + 1024), 16, 0, 0);
    };

    ISSUE(0, 0);
    ISSUE(1, 1);

    float acc[2][4] = {{0}, {0}};
    f32x4 ps0 = (f32x4){0, 0, 0, 0}, ps1 = (f32x4){0, 0, 0, 0};   // deferred scores
    float pw = 0.0f;                                               // deferred wv

    // per-lane swizzled ds_read bases (elements); slot/t are imm offsets at call sites
    const __bf16* kaddr[4];
#pragma unroll
    for (int ks = 0; ks < 4; ks++)
        kaddr[ks] = kbuf + n16 * 128 + (((ks * 4 + q) ^ n16) << 3);
    const float* wsl = wv + jb0 + n16;

    // one t-step: issue 8 MFMAs for (slot,t) at element offset `off`,
    // then the sigmoid of the PREVIOUS step (ps/pw already final).
    auto STEP = [&](int off, float wnew) {
        f32x4 s0 = (f32x4){0, 0, 0, 0}, s1 = (f32x4){0, 0, 0, 0};
        __builtin_amdgcn_s_setprio(1);
#pragma unroll
        for (int ks = 0; ks < 4; ks++) {
            bf16x8 bf = *(const bf16x8*)(kaddr[ks] + off);
            s0 = __builtin_amdgcn_mfma_f32_16x16x32_bf16(qf[0][ks], bf, s0, 0, 0, 0);
            s1 = __builtin_amdgcn_mfma_f32_16x16x32_bf16(qf[1][ks], bf, s1, 0, 0, 0);
        }
        __builtin_amdgcn_s_setprio(0);
#pragma unroll
        for (int r = 0; r < 4; r++) {
            // qb pre-scaled by -log2e: sigmoid(s) = rcp(1 + exp2(s'))
            acc[0][r] += __builtin_amdgcn_rcpf(1.0f + __builtin_amdgcn_exp2f(ps0[r])) * pw;
            acc[1][r] += __builtin_amdgcn_rcpf(1.0f + __builtin_amdgcn_exp2f(ps1[r])) * pw;
        }
        ps0 = s0; ps1 = s1; pw = wnew;
    };

    // one pair of chunks (2p, 2p+1) living in slots sb, sb+1
    auto PAIR = [&](int p, int sb) {
        asm volatile("s_waitcnt vmcnt(0)" ::: "memory");
        __builtin_amdgcn_sched_barrier(0);
        __builtin_amdgcn_s_barrier();
        const int c2 = (2 * p + 2 < 64) ? 2 * p + 2 : 62;   // tail: re-stage (harmless)
        const int c3 = (2 * p + 3 < 64) ? 2 * p + 3 : 63;
        ISSUE(c2, sb ^ 2);
        ISSUE(c3, (sb ^ 2) + 1);
        float w0 = wsl[p * 64];
        float w1 = wsl[p * 64 + 16];
        float w2 = wsl[p * 64 + 32];
        float w3 = wsl[p * 64 + 48];
        STEP(sb * 4096,        w0);
        STEP(sb * 4096 + 2048, w1);
        STEP(sb * 4096 + 4096, w2);
        STEP(sb * 4096 + 6144, w3);
    };

    for (int p = 0; p < 32; p += 2) {
        PAIR(p, 0);
        PAIR(p + 1, 2);
    }

    // flush the last deferred t-step
#pragma unroll
    for (int r = 0; r < 4; r++) {
        acc[0][r] += __builtin_amdgcn_rcpf(1.0f + __builtin_amdgcn_exp2f(ps0[r])) * pw;
        acc[1][r] += __builtin_amdgcn_rcpf(1.0f + __builtin_amdgcn_exp2f(ps1[r])) * pw;
    }

    // per-wave reduction over the 16 k-lanes; rows unique per wave -> direct store
#pragma unroll
    for (int mt = 0; mt < 2; mt++)
#pragma unroll
        for (int r = 0; r < 4; r++) {
            float v = acc[mt][r];
            v += __shfl_xor(v, 1, 64);
            v += __shfl_xor(v, 2, 64);
            v += __shfl_xor(v, 4, 64);
            v += __shfl_xor(v, 8, 64);
            if (n16 == 0) partial[sp * N_ROWS + row0 + mt * 16 + q * 4 + r] = v;
        }
}

// ---- kernel 3: deterministic reduce over 8 slices + b_fc ----
__global__ void reduce_out(const float* __restrict__ partial, const float* __restrict__ b_fc,
                           float* __restrict__ out) {
    int i = blockIdx.x * 256 + threadIdx.x;
    float v = b_fc[0];
#pragma unroll
    for (int s = 0; s < 8; s++) v += partial[s * N_ROWS + i];
    out[i] = v;
}

extern "C" void kernel_launch(void* const* d_in, const int* in_sizes, int n_in,
                              void* d_out, int out_size, void* d_ws, size_t ws_size,
                              hipStream_t stream) {
    const float* x       = (const float*)d_in[0];
    // d_in[1] = decay_value (unused by reference)
    const float* W_token = (const float*)d_in[2];
    const float* b_token = (const float*)d_in[3];
    const float* W_qkv   = (const float*)d_in[4];
    const float* b_qkv   = (const float*)d_in[5];
    const float* W_fc    = (const float*)d_in[6];
    const float* b_fc    = (const float*)d_in[7];
    float* out = (float*)d_out;
    char* ws = (char*)d_ws;

    __bf16* WcS = (__bf16*)(ws + OFF_WCS);
    float*  bc  = (float*)(ws + OFF_BC);
    __bf16* qb  = (__bf16*)(ws + OFF_QB);
    __bf16* kb  = (__bf16*)(ws + OFF_KB);
    float*  wv  = (float*)(ws + OFF_WV);
    float*  part = (float*)(ws + OFF_PART);

    prep<<<288, 256, 0, stream>>>(W_token, W_qkv, b_token, b_qkv, WcS, bc);
    gemm_qkv<<<dim3(256, 3), 256, 0, stream>>>(x, WcS, bc, W_fc, qb, kb, wv);
    attn<<<1024, 256, 0, stream>>>(qb, kb, wv, part);
    reduce_out<<<64, 256, 0, stream>>>(part, b_fc, out);
}

// Round 8
// 204.037 us; speedup vs baseline: 1.1489x; 1.1489x over previous
//
#include <hip/hip_runtime.h>
#include <hip/hip_bf16.h>
#include <stdint.h>

#define N_ROWS 16384

typedef __bf16 bf16x8 __attribute__((ext_vector_type(8)));
typedef float f32x4 __attribute__((ext_vector_type(4)));

#define AS1 __attribute__((address_space(1)))
#define AS3 __attribute__((address_space(3)))

// ---------------- ws layout (bytes) ----------------
// WcS : (W_token@W_qkv)^T bf16 [384][768], 8-elt chunks XOR-swizzled   589824
// bc  : f32 [384]  (b_token@W_qkv + b_qkv)                               1536
// qb  : bf16 [16384][128]  (q * -log2e)                               4194304
// kb  : bf16 [16384][128]  (XOR-swizzled, staged via global_load_lds) 4194304
// wv  : f32  [16384]  ((v+bias) . W_fc)                                 65536
// part: f32  [8][16384]                                                524288
#define OFF_WCS  0u
#define OFF_BC   589824u
#define OFF_QB   591360u
#define OFF_KB   4785664u
#define OFF_WV   8979968u
#define OFF_PART 9045504u

// ---- kernel 0: Wc = W_token @ W_qkv -> bf16, [n][768] with 8-elt chunk XOR swizzle;
//      bc = b_token @ W_qkv + b_qkv ----
__global__ void prep(const float* __restrict__ Wt, const float* __restrict__ Wq,
                     const float* __restrict__ bt, const float* __restrict__ bq,
                     __bf16* __restrict__ WcS, float* __restrict__ bc) {
    int u = blockIdx.x * 256 + threadIdx.x;          // [0, 768*96)
    if (u < 768 * 96) {
        int k = u / 96, n4 = u % 96;
        float s[4] = {0, 0, 0, 0};
        const float* wtp = Wt + k * 128;
        const float* wqp = Wq + n4 * 4;
#pragma unroll 8
        for (int d = 0; d < 128; d++) {
            float a = wtp[d];
            float4 b = *(const float4*)(wqp + d * 384);
            s[0] += a * b.x; s[1] += a * b.y; s[2] += a * b.z; s[3] += a * b.w;
        }
        int kb_ = k >> 6, c = (k >> 3) & 7, k7 = k & 7;
#pragma unroll
        for (int j = 0; j < 4; j++) {
            int n = n4 * 4 + j;
            WcS[n * 768 + kb_ * 64 + ((c ^ (n & 7)) << 3) + k7] = (__bf16)s[j];
        }
    }
    if (u < 384) {
        float s = bq[u];
        for (int d = 0; d < 128; d++) s += bt[d] * Wq[d * 384 + u];
        bc[u] = s;
    }
}

// ---- kernel 1: qkv = bf16(x) @ Wc + bc via LDS-staged tiled GEMM ----
// BM=64, BN=128, BK=64; grid (256, 3); sp aligns with q / k / v+wv epilogues.
__launch_bounds__(256)
__global__ void gemm_qkv(const float* __restrict__ x, const __bf16* __restrict__ WcS,
                         const float* __restrict__ bc, const float* __restrict__ W_fc,
                         __bf16* __restrict__ qb, __bf16* __restrict__ kb,
                         float* __restrict__ wv) {
    __shared__ float  Asm[64 * 64];    // fp32 A tile, 32B-pair XOR-swizzled
    __shared__ __bf16 Bsm[128 * 64];   // bf16 B tile, 16B-chunk XOR-swizzled
    __shared__ float  wred[64];
    const int tid = threadIdx.x, wave = tid >> 6, lane = tid & 63;
    const int n16 = lane & 15, q = lane >> 4;
    const int mh = wave >> 1, nw = wave & 1;
    const int row0 = blockIdx.x * 64;
    const int sp = blockIdx.y;

    // per-lane staging source pointers (swizzle baked into the global address)
    const char* aptr[4];
    const char* bptr[4];
    {
        int p = (lane & 15) >> 1, half = lane & 1;
#pragma unroll
        for (int i = 0; i < 4; i++) {
            int ar = row0 + wave * 16 + i * 4 + (lane >> 4);
            aptr[i] = (const char*)x + (size_t)ar * 3072 + ((p ^ (ar & 7)) * 8 + half * 4) * 4;
            int br = sp * 128 + wave * 32 + i * 8 + (lane >> 3);
            bptr[i] = (const char*)WcS + (size_t)br * 1536 + (lane & 7) * 16;
        }
    }
    f32x4 acc[2][4];
#pragma unroll
    for (int mt = 0; mt < 2; mt++)
#pragma unroll
        for (int t = 0; t < 4; t++) acc[mt][t] = (f32x4){0, 0, 0, 0};

    for (int kbi = 0; kbi < 12; kbi++) {
#pragma unroll
        for (int i = 0; i < 4; i++)
            __builtin_amdgcn_global_load_lds((const AS1 void*)(aptr[i] + kbi * 256),
                (AS3 void*)((char*)Asm + wave * 4096 + i * 1024), 16, 0, 0);
#pragma unroll
        for (int i = 0; i < 4; i++)
            __builtin_amdgcn_global_load_lds((const AS1 void*)(bptr[i] + kbi * 128),
                (AS3 void*)((char*)Bsm + wave * 4096 + i * 1024), 16, 0, 0);
        __syncthreads();
#pragma unroll
        for (int ks = 0; ks < 2; ks++) {
            const int swz = ((ks * 4 + q) ^ (n16 & 7)) << 3;
            bf16x8 af[2];
#pragma unroll
            for (int mt = 0; mt < 2; mt++) {
                const float* ap = Asm + (mh * 32 + mt * 16 + n16) * 64 + swz;
                f32x4 a0 = *(const f32x4*)ap;
                f32x4 a1 = *(const f32x4*)(ap + 4);
                bf16x8 t;
                t[0] = (__bf16)a0[0]; t[1] = (__bf16)a0[1]; t[2] = (__bf16)a0[2]; t[3] = (__bf16)a0[3];
                t[4] = (__bf16)a1[0]; t[5] = (__bf16)a1[1]; t[6] = (__bf16)a1[2]; t[7] = (__bf16)a1[3];
                af[mt] = t;
            }
#pragma unroll
            for (int t = 0; t < 4; t++) {
                bf16x8 bf = *(const bf16x8*)(Bsm + (nw * 64 + t * 16 + n16) * 64 + swz);
                acc[0][t] = __builtin_amdgcn_mfma_f32_16x16x32_bf16(af[0], bf, acc[0][t], 0, 0, 0);
                acc[1][t] = __builtin_amdgcn_mfma_f32_16x16x32_bf16(af[1], bf, acc[1][t], 0, 0, 0);
            }
        }
        __syncthreads();
    }

    // epilogue: cols of this block = sp*128 + nw*64 + t*16 + n16
    const int clb = nw * 64 + n16;
    if (sp == 0) {
#pragma unroll
        for (int t = 0; t < 4; t++) {
            int cl = clb + t * 16;
            float bcv = bc[cl];
#pragma unroll
            for (int mt = 0; mt < 2; mt++)
#pragma unroll
                for (int r = 0; r < 4; r++) {
                    int row = row0 + mh * 32 + mt * 16 + q * 4 + r;
                    qb[row * 128 + cl] = (__bf16)((acc[mt][t][r] + bcv) * -1.44269504088896f);
                }
        }
    } else if (sp == 1) {
        // kb XOR-swizzled (16-chunk index ^ row&15) so attn's linear
        // global_load_lds + swizzled ds_read is bank-conflict-free.
#pragma unroll
        for (int t = 0; t < 4; t++) {
            int d = clb + t * 16;
            float bcv = bc[128 + d];
#pragma unroll
            for (int mt = 0; mt < 2; mt++)
#pragma unroll
                for (int r = 0; r < 4; r++) {
                    int row = row0 + mh * 32 + mt * 16 + q * 4 + r;
                    kb[row * 128 + (((d >> 3) ^ (row & 15)) << 3) + (d & 7)] = (__bf16)(acc[mt][t][r] + bcv);
                }
        }
    } else {
        float wacc[2][4] = {{0, 0, 0, 0}, {0, 0, 0, 0}};
#pragma unroll
        for (int t = 0; t < 4; t++) {
            int cl = clb + t * 16;
            float bcv = bc[256 + cl];
            float wf = W_fc[cl];
#pragma unroll
            for (int mt = 0; mt < 2; mt++)
#pragma unroll
                for (int r = 0; r < 4; r++) wacc[mt][r] += (acc[mt][t][r] + bcv) * wf;
        }
        float vred[2][4];
#pragma unroll
        for (int mt = 0; mt < 2; mt++)
#pragma unroll
            for (int r = 0; r < 4; r++) {
                float v = wacc[mt][r];
                v += __shfl_xor(v, 1, 64);
                v += __shfl_xor(v, 2, 64);
                v += __shfl_xor(v, 4, 64);
                v += __shfl_xor(v, 8, 64);
                vred[mt][r] = v;
                if (nw == 0 && n16 == 0) wred[mh * 32 + mt * 16 + q * 4 + r] = v;
            }
        __syncthreads();
        if (nw == 1 && n16 == 0) {
#pragma unroll
            for (int mt = 0; mt < 2; mt++)
#pragma unroll
                for (int r = 0; r < 4; r++) {
                    int lr = mh * 32 + mt * 16 + q * 4 + r;
                    wv[row0 + lr] = wred[lr] + vred[mt][r];
                }
        }
    }
}

// ---- kernel 2: partial[sp][i] = sum_{j in slice sp} sigmoid(q_i.k_j) * wv_j ----
// v8 = R6 (best, 91.5us) + three surgical cuts, flat macros only (R7 lesson:
// lambdas caused 135 MB of scratch spill traffic):
//  1. wlds dropped -> LDS exactly 32 KB (kbuf ring only). wv comes via 2
//     per-lane register loads per chunk, prefetched ONE CHUNK AHEAD and
//     order-pinned (sched_barrier) before the staging pair, so each iter's
//     vmem sequence is [2 wv][2 stage] and the manual vmcnt(4) stays exact.
//  2. ping-pong psE/psO deferred-score registers (chunk-parity compile-time
//     under unroll 4) -> kills 8 v_mov per STEP.
//  3. wv regs double-banked A/B by chunk parity -> no copies.
// Schedule per chunk jc: [wv prefetch jc+1][ISSUE jc+2][vmcnt(4)][s_barrier]
// [STEP t0][STEP t1]; deferred sigmoid consumes the previous STEP's scores.
__launch_bounds__(256, 4)
__global__ void attn(const __bf16* __restrict__ qb, const __bf16* __restrict__ kb,
                     const float* __restrict__ wv, float* __restrict__ partial) {
    __shared__ __bf16 kbuf[4 * 32 * 128];   // 32 KB ring, sole LDS use
    const int tid = threadIdx.x;
    const int wave = tid >> 6, lane = tid & 63;
    const int n16 = lane & 15, q = lane >> 4;
    const int bid = blockIdx.x;
    const int sp = bid & 7;                  // XCD-pinned k-slice
    const int rb = bid >> 3;                 // [0,128) row block
    const int row0 = rb * 128 + wave * 32;
    const int jb0 = sp * 2048;

    // q fragments: 32 rows x 128 d, resident in 32 VGPRs
    bf16x8 qf[2][4];
#pragma unroll
    for (int mt = 0; mt < 2; mt++)
#pragma unroll
        for (int ks = 0; ks < 4; ks++)
            qf[mt][ks] = *(const bf16x8*)(qb + (size_t)(row0 + mt * 16 + n16) * 128 + ks * 32 + q * 8);
    __builtin_amdgcn_sched_barrier(0);

    // each wave stages 2 KB (2 x 1 KB) of each 8 KB chunk
#define ISSUE(c, slot)                                                                  \
    {                                                                                   \
        const char* gsrc = (const char*)kb + (size_t)(jb0 + (c) * 32) * 256 + wave * 2048; \
        char* gdst = (char*)kbuf + (slot) * 8192 + wave * 2048;                          \
        __builtin_amdgcn_global_load_lds((const AS1 void*)(gsrc + lane * 16),            \
                                         (AS3 void*)gdst, 16, 0, 0);                     \
        __builtin_amdgcn_global_load_lds((const AS1 void*)(gsrc + 1024 + lane * 16),     \
                                         (AS3 void*)(gdst + 1024), 16, 0, 0);            \
    }

    const float* wsl = wv + jb0 + n16;
    // wv for chunk 0 (even chunk -> A bank), then chunks 0,1 staged
    float wnA0 = wsl[0], wnA1 = wsl[16];
    float wnB0 = 0.0f, wnB1 = 0.0f;
    __builtin_amdgcn_sched_barrier(0);
    ISSUE(0, 0);
    ISSUE(1, 1);

    float acc[2][4] = {{0}, {0}};
    f32x4 psE0 = (f32x4){0, 0, 0, 0}, psE1 = (f32x4){0, 0, 0, 0};
    f32x4 psO0 = (f32x4){0, 0, 0, 0}, psO1 = (f32x4){0, 0, 0, 0};
    float pw = 0.0f;   // deferred wv weight (first consume: sigmoid(0)*0 = 0)

    // per-lane swizzled ds_read bases (elements); slot/t are imm offsets
    const __bf16* kaddr[4];
#pragma unroll
    for (int ks = 0; ks < 4; ks++)
        kaddr[ks] = kbuf + n16 * 128 + (((ks * 4 + q) ^ n16) << 3);

    // one t-step: MFMA scores into SW*, sigmoid of previous step's SR* (final),
    // then advance the deferred weight.
#define STEP(SW0, SW1, SR0, SR1, OFFB, WCUR)                                            \
    {                                                                                   \
        SW0 = (f32x4){0, 0, 0, 0};                                                      \
        SW1 = (f32x4){0, 0, 0, 0};                                                      \
        __builtin_amdgcn_s_setprio(1);                                                  \
        _Pragma("unroll")                                                               \
        for (int ks = 0; ks < 4; ks++) {                                                \
            bf16x8 bf = *(const bf16x8*)(kaddr[ks] + (OFFB));                           \
            SW0 = __builtin_amdgcn_mfma_f32_16x16x32_bf16(qf[0][ks], bf, SW0, 0, 0, 0); \
            SW1 = __builtin_amdgcn_mfma_f32_16x16x32_bf16(qf[1][ks], bf, SW1, 0, 0, 0); \
        }                                                                               \
        __builtin_amdgcn_s_setprio(0);                                                  \
        _Pragma("unroll")                                                               \
        for (int r = 0; r < 4; r++) {                                                   \
            acc[0][r] += __builtin_amdgcn_rcpf(1.0f + __builtin_amdgcn_exp2f(SR0[r])) * pw; \
            acc[1][r] += __builtin_amdgcn_rcpf(1.0f + __builtin_amdgcn_exp2f(SR1[r])) * pw; \
        }                                                                               \
        pw = (WCUR);                                                                    \
    }

#pragma unroll 4
    for (int jc = 0; jc < 64; jc++) {
        // wv prefetch for chunk jc+1 into the bank of (jc+1)'s parity
        const int jn1 = (jc + 1 < 64) ? jc + 1 : 63;
        if (((jc + 1) & 1) == 0) { wnA0 = wsl[jn1 * 32]; wnA1 = wsl[jn1 * 32 + 16]; }
        else                     { wnB0 = wsl[jn1 * 32]; wnB1 = wsl[jn1 * 32 + 16]; }
        __builtin_amdgcn_sched_barrier(0);
        // K staging 2 ahead; tail re-stages a finished chunk (values unused)
        const int jn2 = (jc + 2 < 64) ? jc + 2 : 62;
        ISSUE(jn2, (jc + 2) & 3);
        __builtin_amdgcn_sched_barrier(0);
        // wait chunk jc complete; iter jc's own 4 loads (2 wv + 2 stage) stay in flight
        asm volatile("s_waitcnt vmcnt(4)" ::: "memory");
        __builtin_amdgcn_sched_barrier(0);
        __builtin_amdgcn_s_barrier();

        const int sb = (jc & 3) * 4096;   // compile-time under unroll-4
        if ((jc & 1) == 0) {
            STEP(psE0, psE1, psO0, psO1, sb, wnA0);
            STEP(psO0, psO1, psE0, psE1, sb + 2048, wnA1);
        } else {
            STEP(psE0, psE1, psO0, psO1, sb, wnB0);
            STEP(psO0, psO1, psE0, psE1, sb + 2048, wnB1);
        }
    }
#undef STEP
#undef ISSUE

    // flush the last deferred t-step (last written = psO, weight = pw)
#pragma unroll
    for (int r = 0; r < 4; r++) {
        acc[0][r] += __builtin_amdgcn_rcpf(1.0f + __builtin_amdgcn_exp2f(psO0[r])) * pw;
        acc[1][r] += __builtin_amdgcn_rcpf(1.0f + __builtin_amdgcn_exp2f(psO1[r])) * pw;
    }

    // per-wave reduction over the 16 k-lanes; rows unique per wave -> direct store
#pragma unroll
    for (int mt = 0; mt < 2; mt++)
#pragma unroll
        for (int r = 0; r < 4; r++) {
            float v = acc[mt][r];
            v += __shfl_xor(v, 1, 64);
            v += __shfl_xor(v, 2, 64);
            v += __shfl_xor(v, 4, 64);
            v += __shfl_xor(v, 8, 64);
            if (n16 == 0) partial[sp * N_ROWS + row0 + mt * 16 + q * 4 + r] = v;
        }
}

// ---- kernel 3: deterministic reduce over 8 slices + b_fc ----
__global__ void reduce_out(const float* __restrict__ partial, const float* __restrict__ b_fc,
                           float* __restrict__ out) {
    int i = blockIdx.x * 256 + threadIdx.x;
    float v = b_fc[0];
#pragma unroll
    for (int s = 0; s < 8; s++) v += partial[s * N_ROWS + i];
    out[i] = v;
}

extern "C" void kernel_launch(void* const* d_in, const int* in_sizes, int n_in,
                              void* d_out, int out_size, void* d_ws, size_t ws_size,
                              hipStream_t stream) {
    const float* x       = (const float*)d_in[0];
    // d_in[1] = decay_value (unused by reference)
    const float* W_token = (const float*)d_in[2];
    const float* b_token = (const float*)d_in[3];
    const float* W_qkv   = (const float*)d_in[4];
    const float* b_qkv   = (const float*)d_in[5];
    const float* W_fc    = (const float*)d_in[6];
    const float* b_fc    = (const float*)d_in[7];
    float* out = (float*)d_out;
    char* ws = (char*)d_ws;

    __bf16* WcS = (__bf16*)(ws + OFF_WCS);
    float*  bc  = (float*)(ws + OFF_BC);
    __bf16* qb  = (__bf16*)(ws + OFF_QB);
    __bf16* kb  = (__bf16*)(ws + OFF_KB);
    float*  wv  = (float*)(ws + OFF_WV);
    float*  part = (float*)(ws + OFF_PART);

    prep<<<288, 256, 0, stream>>>(W_token, W_qkv, b_token, b_qkv, WcS, bc);
    gemm_qkv<<<dim3(256, 3), 256, 0, stream>>>(x, WcS, bc, W_fc, qb, kb, wv);
    attn<<<1024, 256, 0, stream>>>(qb, kb, wv, part);
    reduce_out<<<64, 256, 0, stream>>>(part, b_fc, out);
}